// Round 1
// baseline (9319.872 us; speedup 1.0000x reference)
//
#include <hip/hip_runtime.h>

typedef short short8 __attribute__((ext_vector_type(8)));
typedef float f32x4 __attribute__((ext_vector_type(4)));

#define NB 64
#define NT 1024
#define NI 128
#define NH 512

__device__ __forceinline__ unsigned short f2bf(float f) {
  union { float f; unsigned u; } v; v.f = f;
  unsigned u = v.u;
  return (unsigned short)((u + 0x7FFFu + ((u >> 16) & 1u)) >> 16);
}

__device__ __forceinline__ f32x4 mfma16(short8 a, short8 b, f32x4 c) {
  return __builtin_amdgcn_mfma_f32_16x16x32_bf16(a, b, c, 0, 0, 0);
}

// Build combined recurrent matrix M[o][k] (512x512 bf16), scales folded in.
// rows o<256:  A1*W11[o,k]        | A1*0.5*W21[o,k-256]
// rows o>=256: A1*0.5*W12[o-256,k]| A1*W22[o-256,k-256]
__global__ __launch_bounds__(256) void buildM_k(
    const float* __restrict__ W11, const float* __restrict__ W22,
    const float* __restrict__ W12, const float* __restrict__ W21,
    unsigned short* __restrict__ M) {
  int idx = blockIdx.x * 256 + threadIdx.x;  // 262144 total
  int o = idx >> 9, k = idx & 511;
  const float A1f = (float)(16.67 / 100.0);
  float v;
  if (o < 256) {
    v = (k < 256) ? A1f * W11[(o << 8) + k]
                  : A1f * 0.5f * W21[(o << 8) + (k - 256)];
  } else {
    int o2 = o - 256;
    v = (k < 256) ? A1f * 0.5f * W12[(o2 << 8) + k]
                  : A1f * W22[(o2 << 8) + (k - 256)];
  }
  M[idx] = f2bf(v);
}

__global__ __launch_bounds__(256) void buildWiT_k(const float* __restrict__ Wi,
                                                  float* __restrict__ WiT) {
  int idx = blockIdx.x * 256 + threadIdx.x;  // 32768 = 128*256, WiT[k][o]
  int k = idx >> 8, o = idx & 255;
  WiT[idx] = Wi[o * 128 + k];
}

// xp'[t][b][o] = A1 * (sum_i x[b][t][i]*Wi[o][i] + bi[o]), f32.
// One block = 64 consecutive rows R=b*1024+t; 256 threads: wave=rowgroup(16), lane->4 cols.
__global__ __launch_bounds__(256) void xproj_k(
    const float* __restrict__ x, const float* __restrict__ WiT,
    const float* __restrict__ bi, float* __restrict__ xp) {
  __shared__ float xs[128 * 68];  // x transposed [k][r], pad 68 for banks
  int tid = threadIdx.x;
  int wv = tid >> 6;   // 0..3 row-group (16 rows each)
  int c = tid & 63;    // col-group: cols 4c..4c+3
  long Rbase = (long)blockIdx.x * 64;
  const float* xg = x + Rbase * 128;
  #pragma unroll
  for (int i = 0; i < 32; i++) {
    int idx = tid + 256 * i;       // idx = r*128 + k
    int r = idx >> 7, k = idx & 127;
    xs[k * 68 + r] = xg[idx];
  }
  __syncthreads();
  float acc[4][16];
  #pragma unroll
  for (int a = 0; a < 4; a++)
    #pragma unroll
    for (int b = 0; b < 16; b++) acc[a][b] = 0.f;
  for (int k = 0; k < 128; k++) {
    f32x4 w4 = *(const f32x4*)(WiT + k * 256 + 4 * c);
    const float* xr = &xs[k * 68 + 16 * wv];
    #pragma unroll
    for (int rr = 0; rr < 4; rr++) {
      f32x4 xv = *(const f32x4*)(xr + 4 * rr);
      #pragma unroll
      for (int cc = 0; cc < 4; cc++) {
        #pragma unroll
        for (int u = 0; u < 4; u++)
          acc[cc][4 * rr + u] = fmaf(w4[cc], xv[u], acc[cc][4 * rr + u]);
      }
    }
  }
  f32x4 bv = *(const f32x4*)(bi + 4 * c);
  const float A1f = (float)(16.67 / 100.0);
  #pragma unroll
  for (int rr = 0; rr < 16; rr++) {
    long R = Rbase + 16 * wv + rr;
    int b = (int)(R >> 10), t = (int)(R & 1023);
    f32x4 o;
    #pragma unroll
    for (int cc = 0; cc < 4; cc++) o[cc] = A1f * (acc[cc][rr] + bv[cc]);
    *(f32x4*)(xp + ((long)(t * 64 + b) << 8) + 4 * c) = o;
  }
}

// Recurrent kernel: 4 blocks x 512 threads. Block g: batches 16g..16g+15.
// wave w owns output cols [64w, 64w+64): 4 n-tiles. K = 512 = 16 k-tiles.
// B-frags: kt 0..5 pinned in registers, kt 6..15 streamed from L2 (3-deep).
__global__ __launch_bounds__(512, 2) void rnn_k(
    const unsigned short* __restrict__ M, const float* __restrict__ xp,
    float* __restrict__ out) {
  const int g = blockIdx.x;
  const int tid = threadIdx.x;
  const int w = tid >> 6;
  const int lane = tid & 63;
  const int n = lane & 15;   // B col within tile / A row (same bits)
  const int q = lane >> 4;   // 0..3

  __shared__ __align__(16) unsigned short hb[2][16 * 512];
  #pragma unroll
  for (int i = 0; i < 16; i++) hb[0][tid + 512 * i] = 0;

  const float C1 = (float)(1.0 - 16.67 / 100.0);

  // pinned B fragments (kt = 0..5) + stream base pointers (kt>=6)
  short8 Bp[4][6];
  const short8* sp[4];
  #pragma unroll
  for (int nt = 0; nt < 4; nt++) {
    const unsigned short* mb = M + (w * 64 + nt * 16 + n) * 512 + q * 8;
    #pragma unroll
    for (int kt = 0; kt < 6; kt++) Bp[nt][kt] = *(const short8*)(mb + kt * 32);
    sp[nt] = (const short8*)(mb + 6 * 32);  // kt stride = 4 short8
  }

  float hprev[4][4];
  #pragma unroll
  for (int a = 0; a < 4; a++)
    #pragma unroll
    for (int b = 0; b < 4; b++) hprev[a][b] = 0.f;

  const bool hasxp = (w < 4);
  const float* xpb = xp + ((g * 16 + 4 * q) << 8) + w * 64 + n;
  float xpv[4][4], xpn[4][4];
  #pragma unroll
  for (int a = 0; a < 4; a++)
    #pragma unroll
    for (int b = 0; b < 4; b++) { xpv[a][b] = 0.f; xpn[a][b] = 0.f; }
  if (hasxp) {
    #pragma unroll
    for (int nt = 0; nt < 4; nt++)
      #pragma unroll
      for (int j = 0; j < 4; j++) {
        xpv[nt][j] = __builtin_nontemporal_load(xpb + 0 * 16384 + j * 256 + nt * 16);
        xpn[nt][j] = __builtin_nontemporal_load(xpb + 1 * 16384 + j * 256 + nt * 16);
      }
  }

  float* outb = out + (long)(g * 16 + 4 * q) * (NT * NH) + w * 64 + n;

  short8 s0[4], s1[4], s2[4];
  #pragma unroll
  for (int nt = 0; nt < 4; nt++) { s0[nt] = sp[nt][0]; s1[nt] = sp[nt][4]; s2[nt] = sp[nt][8]; }

  __syncthreads();

  #pragma unroll 1
  for (int t = 0; t < NT; t++) {
    const unsigned short* hr = hb[t & 1];
    unsigned short* hw = hb[(t + 1) & 1];

    f32x4 acc[4];
    #pragma unroll
    for (int nt = 0; nt < 4; nt++) acc[nt] = (f32x4){0.f, 0.f, 0.f, 0.f};

    auto aload = [&](int kt) -> short8 {
      unsigned e = (unsigned)((n * 512 + kt * 32 + q * 8) ^ ((n & 7) << 3));
      return *(const short8*)(hr + e);
    };

    // pinned k-tiles 0..5
    #pragma unroll
    for (int kt = 0; kt < 6; kt++) {
      short8 a = aload(kt);
      #pragma unroll
      for (int nt = 0; nt < 4; nt++) acc[nt] = mfma16(a, Bp[nt][kt], acc[nt]);
    }
    // streamed k-tiles 6..15, 3-deep rolling prefetch
    {
      short8 a;
      a = aload(6);
      #pragma unroll
      for (int nt = 0; nt < 4; nt++) acc[nt] = mfma16(a, s0[nt], acc[nt]);
      #pragma unroll
      for (int nt = 0; nt < 4; nt++) s0[nt] = sp[nt][12];  // kt9
      a = aload(7);
      #pragma unroll
      for (int nt = 0; nt < 4; nt++) acc[nt] = mfma16(a, s1[nt], acc[nt]);
      #pragma unroll
      for (int nt = 0; nt < 4; nt++) s1[nt] = sp[nt][16];  // kt10
      a = aload(8);
      #pragma unroll
      for (int nt = 0; nt < 4; nt++) acc[nt] = mfma16(a, s2[nt], acc[nt]);
      #pragma unroll
      for (int nt = 0; nt < 4; nt++) s2[nt] = sp[nt][20];  // kt11
      a = aload(9);
      #pragma unroll
      for (int nt = 0; nt < 4; nt++) acc[nt] = mfma16(a, s0[nt], acc[nt]);
      #pragma unroll
      for (int nt = 0; nt < 4; nt++) s0[nt] = sp[nt][24];  // kt12
      a = aload(10);
      #pragma unroll
      for (int nt = 0; nt < 4; nt++) acc[nt] = mfma16(a, s1[nt], acc[nt]);
      #pragma unroll
      for (int nt = 0; nt < 4; nt++) s1[nt] = sp[nt][28];  // kt13
      a = aload(11);
      #pragma unroll
      for (int nt = 0; nt < 4; nt++) acc[nt] = mfma16(a, s2[nt], acc[nt]);
      #pragma unroll
      for (int nt = 0; nt < 4; nt++) s2[nt] = sp[nt][32];  // kt14
      a = aload(12);
      #pragma unroll
      for (int nt = 0; nt < 4; nt++) acc[nt] = mfma16(a, s0[nt], acc[nt]);
      #pragma unroll
      for (int nt = 0; nt < 4; nt++) s0[nt] = sp[nt][36];  // kt15
      a = aload(13);
      #pragma unroll
      for (int nt = 0; nt < 4; nt++) acc[nt] = mfma16(a, s1[nt], acc[nt]);
      a = aload(14);
      #pragma unroll
      for (int nt = 0; nt < 4; nt++) acc[nt] = mfma16(a, s2[nt], acc[nt]);
      a = aload(15);
      #pragma unroll
      for (int nt = 0; nt < 4; nt++) acc[nt] = mfma16(a, s0[nt], acc[nt]);
    }
    // reload stream buffers for next step (same addresses, L2-hot)
    #pragma unroll
    for (int nt = 0; nt < 4; nt++) { s0[nt] = sp[nt][0]; s1[nt] = sp[nt][4]; s2[nt] = sp[nt][8]; }

    // epilogue: h_new = relu(C1*h + acc + xp'); write out (f32) + LDS (bf16, swizzled)
    #pragma unroll
    for (int nt = 0; nt < 4; nt++) {
      #pragma unroll
      for (int j = 0; j < 4; j++) {
        float v = fmaf(hprev[nt][j], C1, acc[nt][j] + xpv[nt][j]);
        v = fmaxf(v, 0.f);
        hprev[nt][j] = v;
        __builtin_nontemporal_store(v, outb + (long)j * (NT * NH) + t * NH + nt * 16);
        int mm = 4 * q + j;
        int col = w * 64 + nt * 16 + n;
        hw[(unsigned)((mm * 512 + col) ^ ((mm & 7) << 3))] = f2bf(v);
      }
    }
    // rotate xp double-buffer; prefetch t+2 (2 steps ahead hides HBM latency)
    if (hasxp) {
      int tn = (t + 2 < NT) ? (t + 2) : 0;
      #pragma unroll
      for (int nt = 0; nt < 4; nt++)
        #pragma unroll
        for (int j = 0; j < 4; j++) {
          xpv[nt][j] = xpn[nt][j];
          xpn[nt][j] = __builtin_nontemporal_load(xpb + tn * 16384 + j * 256 + nt * 16);
        }
    }
    __syncthreads();
  }

  // final h1, h2
  const long fbase = (long)NB * NT * NH;  // 33554432
  #pragma unroll
  for (int nt = 0; nt < 4; nt++) {
    #pragma unroll
    for (int j = 0; j < 4; j++) {
      int b = g * 16 + 4 * q + j;
      int col = w * 64 + nt * 16 + n;
      long off = (col < 256) ? (fbase + b * 256 + col)
                             : (fbase + 16384 + b * 256 + (col - 256));
      out[off] = hprev[nt][j];
    }
  }
}

extern "C" void kernel_launch(void* const* d_in, const int* in_sizes, int n_in,
                              void* d_out, int out_size, void* d_ws, size_t ws_size,
                              hipStream_t stream) {
  const float* x   = (const float*)d_in[0];
  // d_in[1] = seq_lengths: forward-identity masking, unused
  const float* Wi  = (const float*)d_in[2];
  const float* bi  = (const float*)d_in[3];
  const float* W11 = (const float*)d_in[4];
  const float* W22 = (const float*)d_in[5];
  const float* W12 = (const float*)d_in[6];
  const float* W21 = (const float*)d_in[7];
  float* out = (float*)d_out;

  unsigned short* M = (unsigned short*)d_ws;                 // 512 KB
  float* WiT = (float*)((char*)d_ws + (512 << 10));          // 128 KB
  float* xp  = (float*)((char*)d_ws + (1 << 20));            // 64 MB

  buildM_k<<<1024, 256, 0, stream>>>(W11, W22, W12, W21, M);
  buildWiT_k<<<128, 256, 0, stream>>>(Wi, WiT);
  xproj_k<<<1024, 256, 0, stream>>>(x, WiT, bi, xp);
  rnn_k<<<4, 512, 0, stream>>>(M, xp, out);
}